// Round 1
// baseline (616.234 us; speedup 1.0000x reference)
//
#include <hip/hip_runtime.h>
#include <math.h>

#define N_OBS_C  1000000
#define N_ROWS_C 8192
#define N_COLS_C 8192
#define RANK_C   64

typedef __attribute__((ext_vector_type(8))) short bf16x8;
typedef __attribute__((ext_vector_type(4))) float f32x4;

// round-to-nearest-even f32 -> bf16 bits
__device__ __forceinline__ unsigned short f2bf(float f) {
  union { float f; unsigned int u; } x; x.f = f;
  unsigned int u = x.u;
  unsigned int r = (u + 0x7fffu + ((u >> 16) & 1u)) >> 16;
  return (unsigned short)r;
}

// ---------------------------------------------------------------------------
// Prep: Vt[n][r] = V[r][n] (f32), plus bf16 copies Ub of U and Vtb of Vt.
// Blocks 0..127: transpose one 64-col slab of V. Blocks 128..191: convert U.
// ---------------------------------------------------------------------------
__global__ void prep_kernel(const float* __restrict__ V, const float* __restrict__ U,
                            float* __restrict__ Vt, unsigned short* __restrict__ Ub,
                            unsigned short* __restrict__ Vtb) {
  int b = blockIdx.x, t = threadIdx.x;
  if (b < 128) {
    __shared__ float tile[64][65];   // +1 pad: conflict-free transpose
    int c0 = b * 64;
#pragma unroll
    for (int i = 0; i < 16; ++i) {
      int idx = i * 256 + t;
      int r = idx >> 6, c = idx & 63;
      tile[r][c] = V[r * N_COLS_C + c0 + c];   // coalesced along n
    }
    __syncthreads();
#pragma unroll
    for (int i = 0; i < 16; ++i) {
      int idx = i * 256 + t;
      int n = idx >> 6, r = idx & 63;
      float v = tile[r][n];
      Vt[(c0 + n) * RANK_C + r]  = v;          // coalesced along r
      Vtb[(c0 + n) * RANK_C + r] = f2bf(v);
    }
  } else {
    int nt  = 64 * 256;
    int tid = (b - 128) * 256 + t;
    for (int i = tid; i < N_ROWS_C * RANK_C; i += nt)
      Ub[i] = f2bf(U[i]);
  }
}

__device__ __forceinline__ void block_reduce_atomic(float v, float* out) {
#pragma unroll
  for (int off = 32; off > 0; off >>= 1) v += __shfl_down(v, off, 64);
  __shared__ float wsum[4];
  int w = threadIdx.x >> 6;
  if ((threadIdx.x & 63) == 0) wsum[w] = v;
  __syncthreads();
  if (threadIdx.x == 0) atomicAdd(out, wsum[0] + wsum[1] + wsum[2] + wsum[3]);
}

// ---------------------------------------------------------------------------
// Fused main kernel. blockIdx % 5 == 0  -> energy (gather) block (2048 total)
// otherwise -> one 128x128 tile of S_U (first 4096) or S_V (next 4096).
// S term: sum_{i,j} S[i,j] * (A[i,:].A[j,:]) with G-tile built by bf16 MFMA.
// ---------------------------------------------------------------------------
__global__ void __launch_bounds__(256)
main_kernel(const float* __restrict__ vals, const int* __restrict__ rows,
            const int* __restrict__ cols, const float* __restrict__ U,
            const float* __restrict__ sigma, const float* __restrict__ S_U,
            const float* __restrict__ S_V, const float* __restrict__ Vt,
            const unsigned short* __restrict__ Ub,
            const unsigned short* __restrict__ Vtb, float* __restrict__ out) {
  const int E_BLOCKS = 2048;
  const int TILES_PER = 64 * 64;   // 4096 tiles of 128x128 per S matrix
  int bid = blockIdx.x;
  int t = threadIdx.x;

  if (bid % 5 == 0) {
    // ---------------- energy term ----------------
    int eb = bid / 5;                       // 0..2047
    float s2 = sigma[0] * sigma[0];
    float local = 0.f;
    int stride = E_BLOCKS * 256;
    for (int n = eb * 256 + t; n < N_OBS_C; n += stride) {
      int r = rows[n], c = cols[n];
      const f32x4* up = (const f32x4*)(U  + (size_t)r * RANK_C);
      const f32x4* vp = (const f32x4*)(Vt + (size_t)c * RANK_C);
      float d0 = 0.f, d1 = 0.f, d2 = 0.f, d3 = 0.f;
#pragma unroll
      for (int k = 0; k < 16; k += 4) {
        f32x4 a0 = up[k],     b0 = vp[k];
        f32x4 a1 = up[k + 1], b1 = vp[k + 1];
        f32x4 a2 = up[k + 2], b2 = vp[k + 2];
        f32x4 a3 = up[k + 3], b3 = vp[k + 3];
        d0 += a0[0]*b0[0] + a0[1]*b0[1] + a0[2]*b0[2] + a0[3]*b0[3];
        d1 += a1[0]*b1[0] + a1[1]*b1[1] + a1[2]*b1[2] + a1[3]*b1[3];
        d2 += a2[0]*b2[0] + a2[1]*b2[1] + a2[2]*b2[2] + a2[3]*b2[3];
        d3 += a3[0]*b3[0] + a3[1]*b3[1] + a3[2]*b3[2] + a3[3]*b3[3];
      }
      float e = vals[n] - ((d0 + d1) + (d2 + d3));
      local += e * e;
    }
    local *= 1.0f / (2.0f * s2);
    if (bid == 0 && t == 0) local += (float)N_OBS_C * logf(s2);
    block_reduce_atomic(local, out);
  } else {
    // ---------------- S quadratic-form tile ----------------
    int sb = (bid / 5) * 4 + (bid % 5 - 1);   // 0..8191
    const float* S; const unsigned short* A;
    if (sb < TILES_PER) { S = S_U; A = Ub; }
    else                { S = S_V; A = Vtb; sb -= TILES_PER; }
    int ti0 = (sb >> 6) * 128;   // tile row origin
    int tj0 = (sb & 63) * 128;   // tile col origin

    int w = t >> 6, lane = t & 63, quad = lane >> 4, lcol = lane & 15;

    // A fragments: A[m = lane&15][k = kh*32 + quad*8 + j] -> 16B row chunk
    bf16x8 af[2][2];
#pragma unroll
    for (int ti = 0; ti < 2; ++ti)
#pragma unroll
      for (int kh = 0; kh < 2; ++kh) {
        int row = ti0 + w * 32 + ti * 16 + lcol;
        af[ti][kh] = *(const bf16x8*)(A + (size_t)row * RANK_C + kh * 32 + quad * 8);
      }
    // B fragments: B[k][n = lane&15] = A[j-row][k] -> same 16B row-chunk form
    bf16x8 bf[8][2];
#pragma unroll
    for (int tj = 0; tj < 8; ++tj)
#pragma unroll
      for (int kh = 0; kh < 2; ++kh) {
        int row = tj0 + tj * 16 + lcol;
        bf[tj][kh] = *(const bf16x8*)(A + (size_t)row * RANK_C + kh * 32 + quad * 8);
      }

    // G strip for this wave: rows [w*32, w*32+32), all 128 cols
    f32x4 acc[2][8];
#pragma unroll
    for (int ti = 0; ti < 2; ++ti)
#pragma unroll
      for (int tj = 0; tj < 8; ++tj) {
        f32x4 z = {0.f, 0.f, 0.f, 0.f};
        z = __builtin_amdgcn_mfma_f32_16x16x32_bf16(af[ti][0], bf[tj][0], z, 0, 0, 0);
        z = __builtin_amdgcn_mfma_f32_16x16x32_bf16(af[ti][1], bf[tj][1], z, 0, 0, 0);
        acc[ti][tj] = z;
      }

    // Stream S tile and dot with G (C layout: col=lane&15, row=quad*4+reg)
    float p0 = 0.f, p1 = 0.f, p2 = 0.f, p3 = 0.f;
#pragma unroll
    for (int ti = 0; ti < 2; ++ti) {
      const float* Sb = S + (size_t)(ti0 + w * 32 + ti * 16 + quad * 4) * N_COLS_C
                          + tj0 + lcol;
#pragma unroll
      for (int tj = 0; tj < 8; ++tj) {
        p0 += Sb[0 * N_COLS_C + tj * 16] * acc[ti][tj][0];
        p1 += Sb[1 * N_COLS_C + tj * 16] * acc[ti][tj][1];
        p2 += Sb[2 * N_COLS_C + tj * 16] * acc[ti][tj][2];
        p3 += Sb[3 * N_COLS_C + tj * 16] * acc[ti][tj][3];
      }
    }
    float local = 0.5f * ((p0 + p1) + (p2 + p3));
    block_reduce_atomic(local, out);
  }
}

extern "C" void kernel_launch(void* const* d_in, const int* in_sizes, int n_in,
                              void* d_out, int out_size, void* d_ws, size_t ws_size,
                              hipStream_t stream) {
  const float* vals  = (const float*)d_in[0];
  const int*   rows  = (const int*)  d_in[1];
  const int*   cols  = (const int*)  d_in[2];
  const float* U     = (const float*)d_in[3];
  const float* V     = (const float*)d_in[4];
  const float* sigma = (const float*)d_in[5];
  const float* S_U   = (const float*)d_in[6];
  const float* S_V   = (const float*)d_in[7];
  float* out = (float*)d_out;

  char* ws = (char*)d_ws;
  float*          Vt  = (float*)ws;                                  // 2 MB
  unsigned short* Ub  = (unsigned short*)(ws + 2u * 1024 * 1024);    // 1 MB
  unsigned short* Vtb = (unsigned short*)(ws + 3u * 1024 * 1024);    // 1 MB

  hipMemsetAsync(d_out, 0, sizeof(float), stream);
  prep_kernel<<<192, 256, 0, stream>>>(V, U, Vt, Ub, Vtb);
  // 2048 energy blocks interleaved 1-in-5 with 8192 S-tile blocks
  main_kernel<<<10240, 256, 0, stream>>>(vals, rows, cols, U, sigma, S_U, S_V,
                                         Vt, Ub, Vtb, out);
}